// Round 7
// baseline (487.106 us; speedup 1.0000x reference)
//
#include <hip/hip_runtime.h>

// Inverse 3D DWT (DB4, periodization), (4,256,256,256) fp32.
// pass 1: axis-1 streaming transform, x -> ws   (scalar, dense-row-coverage grid)
// pass 2: fused axis-2 + axis-3 per (b,d1) slice, ws -> out
// Polyphase: y[2m]   = sum_j s[(m+j-3)&127]*a[j] + w[..]*c[j]
//            y[2m+1] = sum_j s[(m+j-3)&127]*b[j] + w[..]*d[j]
// a[j]=h[6-2j], b[j]=h[7-2j], c[j]=h[2j+1], d[j]=-h[2j].
// NOTE: FILT_DECL owns identifiers a0..a3,b0..b3,c0..c3,d0..d3.

typedef float f32x4 __attribute__((ext_vector_type(4)));   // native vec for NT stores

#define FILT_DECL(h)                                          \
  const float a0 = h[6], a1 = h[4], a2 = h[2], a3 = h[0];     \
  const float b0 = h[7], b1 = h[5], b2 = h[3], b3 = h[1];     \
  const float c0 = h[1], c1 = h[3], c2 = h[5], c3 = h[7];     \
  const float d0 = -h[0], d1 = -h[2], d2 = -h[4], d3 = -h[6];

#define Y0(s0,s1,s2,s3,w0,w1,w2,w3)                                        \
  fmaf(w3, c3, fmaf(w2, c2, fmaf(w1, c1, fmaf(w0, c0,                      \
  fmaf(s3, a3, fmaf(s2, a2, fmaf(s1, a1, s0 * a0)))))))
#define Y1(s0,s1,s2,s3,w0,w1,w2,w3)                                        \
  fmaf(w3, d3, fmaf(w2, d2, fmaf(w1, d1, fmaf(w0, d0,                      \
  fmaf(s3, b3, fmaf(s2, b2, fmaf(s1, b1, s0 * b0)))))))

// ---------------- pass 1: axis 1 (row stride 65536), scalar, in -> tmp ----
// Round-2-proven shape: grid (256,2,4) -> 2048 blocks; each (y,z) covers a
// full 256 KB row densely (256 blocks x 1 KB); only 32 live row-streams.
// Nontemporal loads on x (read-once) keep L3 free for tmp.
__global__ __launch_bounds__(256) void wav_axis1_s(const float* __restrict__ in,
                                                   float* __restrict__ tmp,
                                                   const float* __restrict__ h) {
  const int inner = blockIdx.x * 256 + threadIdx.x;
  const int m0 = blockIdx.y * 64;
  const size_t base = (size_t)blockIdx.z * (256u * 65536u) + (unsigned)inner;
  const float* __restrict__ ps = in + base;
  const float* __restrict__ pw = in + base + (size_t)128 * 65536;
  float* __restrict__ po = tmp + base;
  FILT_DECL(h)
  float s0 = __builtin_nontemporal_load(&ps[(size_t)((m0 - 3) & 127) * 65536]);
  float s1 = __builtin_nontemporal_load(&ps[(size_t)((m0 - 2) & 127) * 65536]);
  float s2 = __builtin_nontemporal_load(&ps[(size_t)((m0 - 1) & 127) * 65536]);
  float w0 = __builtin_nontemporal_load(&pw[(size_t)((m0 - 3) & 127) * 65536]);
  float w1 = __builtin_nontemporal_load(&pw[(size_t)((m0 - 2) & 127) * 65536]);
  float w2 = __builtin_nontemporal_load(&pw[(size_t)((m0 - 1) & 127) * 65536]);
  for (int m = m0; m < m0 + 64; ++m) {
    const float s3 = __builtin_nontemporal_load(&ps[(size_t)m * 65536]);
    const float w3 = __builtin_nontemporal_load(&pw[(size_t)m * 65536]);
    po[(size_t)(2 * m) * 65536] = Y0(s0, s1, s2, s3, w0, w1, w2, w3);
    po[(size_t)(2 * m + 1) * 65536] = Y1(s0, s1, s2, s3, w0, w1, w2, w3);
    s0 = s1; s1 = s2; s2 = s3;
    w0 = w1; w1 = w2; w2 = w3;
  }
}

// ---------------- pass 2: fused axes 2+3 per (b,d1) slice, tmp -> out -----
// Output tile 32 (d2) x 128 (d3); staged footprint 38 x 134 wrapped, 20.8 KB.
// axis-2: one thread per column (dead-slot in-place, thread-exclusive).
// axis-3: 32 rows x 8 pair-chunks = 256 threads, nontemporal f32x4 stores.
__global__ __launch_bounds__(256, 4) void wav_t23(const float* __restrict__ tmp,
                                                  float* __restrict__ out,
                                                  const float* __restrict__ hg) {
  __shared__ float lb[38 * 137];                 // stride 137 (odd) vs banks
  const int t = threadIdx.x;
  const int d2t = blockIdx.x & 7;                // 8 tiles of 32 rows
  const int d3t = blockIdx.x >> 3;               // 2 tiles of 128 cols
  const size_t slice = blockIdx.y;               // b*256 + d1
  const float* __restrict__ src = tmp + slice * 65536;
  FILT_DECL(hg)
  const int mb2 = 16 * d2t - 3;
  const int mb3 = 64 * d3t - 3;

  // stage (38 i2) x (134 i3): s|w halves wrapped per axis
  for (int e = t; e < 38 * 134; e += 256) {
    const int i2 = e / 134, i3 = e - i2 * 134;
    const int g2 = (i2 < 19) ? ((mb2 + i2) & 127) : (128 + ((mb2 + i2 - 19) & 127));
    const int g3 = (i3 < 67) ? ((mb3 + i3) & 127) : (128 + ((mb3 + i3 - 67) & 127));
    lb[i2 * 137 + i3] = src[g2 * 256 + g3];
  }
  __syncthreads();

  // axis-2 down columns (rows 0..18 = s, 19..37 = w); dead-slot in place:
  // pair p: y[2p] -> row p, y[2p+1] -> row 19+p (row p dead after pair p).
  if (t < 134) {
    float S[19], W[19];
#pragma unroll
    for (int i = 0; i < 19; ++i) S[i] = lb[i * 137 + t];
#pragma unroll
    for (int i = 0; i < 19; ++i) W[i] = lb[(19 + i) * 137 + t];
#pragma unroll
    for (int p = 0; p < 16; ++p) {
      lb[p * 137 + t]        = Y0(S[p], S[p+1], S[p+2], S[p+3], W[p], W[p+1], W[p+2], W[p+3]);
      lb[(19 + p) * 137 + t] = Y1(S[p], S[p+1], S[p+2], S[p+3], W[p], W[p+1], W[p+2], W[p+3]);
    }
  }
  __syncthreads();

  // axis-3 along rows; local out row r -> phys row (r&1 ? 19+(r>>1) : r>>1)
  const int r = t >> 3, pc = t & 7;
  const int prow = ((r & 1) ? (19 + (r >> 1)) : (r >> 1)) * 137;
  const int cc0 = 8 * pc;                        // pairs 8*pc .. 8*pc+7
  float S[11], W[11];
#pragma unroll
  for (int i = 0; i < 11; ++i) S[i] = lb[prow + cc0 + i];
#pragma unroll
  for (int i = 0; i < 11; ++i) W[i] = lb[prow + 67 + cc0 + i];
  float y[16];
#pragma unroll
  for (int q = 0; q < 8; ++q) {
    y[2*q]   = Y0(S[q], S[q+1], S[q+2], S[q+3], W[q], W[q+1], W[q+2], W[q+3]);
    y[2*q+1] = Y1(S[q], S[q+1], S[q+2], S[q+3], W[q], W[q+1], W[q+2], W[q+3]);
  }
  float* __restrict__ dst = out + slice * 65536
      + (size_t)(32 * d2t + r) * 256 + 128 * d3t + 16 * pc;
#pragma unroll
  for (int v = 0; v < 4; ++v) {
    f32x4 yv = { y[4*v], y[4*v+1], y[4*v+2], y[4*v+3] };
    __builtin_nontemporal_store(yv, reinterpret_cast<f32x4*>(dst + 4 * v));
  }
}

// ================= fallback 3-pass (verified round 2) =================
__global__ __launch_bounds__(256) void wav_axis1(const float* __restrict__ in,
                                                 float* __restrict__ out,
                                                 const float* __restrict__ h) {
  const int inner = blockIdx.x * 256 + threadIdx.x;
  const int m0 = blockIdx.y * 64;
  const size_t base = (size_t)blockIdx.z * (256u * 65536u) + (unsigned)inner;
  const float* __restrict__ ps = in + base;
  const float* __restrict__ pw = in + base + (size_t)128 * 65536;
  float* __restrict__ po = out + base;
  FILT_DECL(h)
  float s0 = ps[(size_t)((m0 - 3) & 127) * 65536];
  float s1 = ps[(size_t)((m0 - 2) & 127) * 65536];
  float s2 = ps[(size_t)((m0 - 1) & 127) * 65536];
  float w0 = pw[(size_t)((m0 - 3) & 127) * 65536];
  float w1 = pw[(size_t)((m0 - 2) & 127) * 65536];
  float w2 = pw[(size_t)((m0 - 1) & 127) * 65536];
  for (int m = m0; m < m0 + 64; ++m) {
    const float s3 = ps[(size_t)m * 65536];
    const float w3 = pw[(size_t)m * 65536];
    po[(size_t)(2 * m) * 65536] = Y0(s0, s1, s2, s3, w0, w1, w2, w3);
    po[(size_t)(2 * m + 1) * 65536] = Y1(s0, s1, s2, s3, w0, w1, w2, w3);
    s0 = s1; s1 = s2; s2 = s3;
    w0 = w1; w1 = w2; w2 = w3;
  }
}

__global__ __launch_bounds__(256) void wav_axis2(float* __restrict__ buf,
                                                 const float* __restrict__ h) {
  __shared__ float tile[256][32];
  const int t = threadIdx.x;
  const int c = t & 31;
  const int g = t >> 5;
  const size_t slice = (size_t)(blockIdx.x >> 3);
  const int col0 = (blockIdx.x & 7) * 32;
  float* __restrict__ p = buf + slice * 65536 + col0;
#pragma unroll
  for (int i = 0; i < 32; ++i) {
    const int rr = i * 8 + g;
    tile[rr][c] = p[rr * 256 + c];
  }
  __syncthreads();
  FILT_DECL(h)
  const int m0 = g * 16;
  float s0 = tile[(m0 - 3) & 127][c];
  float s1 = tile[(m0 - 2) & 127][c];
  float s2 = tile[(m0 - 1) & 127][c];
  float w0 = tile[128 + ((m0 - 3) & 127)][c];
  float w1 = tile[128 + ((m0 - 2) & 127)][c];
  float w2 = tile[128 + ((m0 - 1) & 127)][c];
#pragma unroll
  for (int m = m0; m < m0 + 16; ++m) {
    const float s3 = tile[m][c];
    const float w3 = tile[128 + m][c];
    p[(2 * m) * 256 + c] = Y0(s0, s1, s2, s3, w0, w1, w2, w3);
    p[(2 * m + 1) * 256 + c] = Y1(s0, s1, s2, s3, w0, w1, w2, w3);
    s0 = s1; s1 = s2; s2 = s3;
    w0 = w1; w1 = w2; w2 = w3;
  }
}

__global__ __launch_bounds__(256) void wav_axis3(float* __restrict__ buf,
                                                 const float* __restrict__ h) {
  __shared__ float tile[512];
  const int t = threadIdx.x;
  float* __restrict__ p = buf + (size_t)blockIdx.x * 512;
  tile[t] = p[t];
  tile[256 + t] = p[256 + t];
  __syncthreads();
  FILT_DECL(h)
  const int rr = t >> 7;
  const int m = t & 127;
  const float* __restrict__ line = tile + rr * 256;
  const float s0 = line[(m - 3) & 127];
  const float s1 = line[(m - 2) & 127];
  const float s2 = line[(m - 1) & 127];
  const float s3 = line[m];
  const float w0 = line[128 + ((m - 3) & 127)];
  const float w1 = line[128 + ((m - 2) & 127)];
  const float w2 = line[128 + ((m - 1) & 127)];
  const float w3 = line[128 + m];
  float2 y;
  y.x = Y0(s0, s1, s2, s3, w0, w1, w2, w3);
  y.y = Y1(s0, s1, s2, s3, w0, w1, w2, w3);
  *reinterpret_cast<float2*>(p + rr * 256 + 2 * m) = y;
}

extern "C" void kernel_launch(void* const* d_in, const int* in_sizes, int n_in,
                              void* d_out, int out_size, void* d_ws, size_t ws_size,
                              hipStream_t stream) {
  const float* x = (const float*)d_in[0];
  const float* h = (const float*)d_in[1];
  float* out = (float*)d_out;
  const size_t need = (size_t)4 * 256 * 256 * 256 * 4;   // 268 MB intermediate

  if (ws_size >= need) {
    float* tmp = (float*)d_ws;
    wav_axis1_s<<<dim3(256, 2, 4), 256, 0, stream>>>(x, tmp, h);
    wav_t23<<<dim3(16, 1024), 256, 0, stream>>>(tmp, out, h);
  } else {
    wav_axis1<<<dim3(256, 2, 4), 256, 0, stream>>>(x, out, h);
    wav_axis2<<<dim3(8192), 256, 0, stream>>>(out, h);
    wav_axis3<<<dim3(131072), 256, 0, stream>>>(out, h);
  }
}

// Round 8
// 244.697 us; speedup vs baseline: 1.9907x; 1.9907x over previous
//
#include <hip/hip_runtime.h>

// Inverse 3D DWT (DB4, periodization), (4,256,256,256) fp32.
// pass 1: axis-1 streaming transform, x -> ws   (scalar, dense-row-coverage grid,
//         nontemporal loads of x only)
// pass 2: fused axis-2 + axis-3 per (b,d1) slice, ws -> out (PLAIN float4 stores;
//         NT stores measured 2.7x write amplification in round 7)
// Polyphase: y[2m]   = sum_j s[(m+j-3)&127]*a[j] + w[..]*c[j]
//            y[2m+1] = sum_j s[(m+j-3)&127]*b[j] + w[..]*d[j]
// a[j]=h[6-2j], b[j]=h[7-2j], c[j]=h[2j+1], d[j]=-h[2j].
// NOTE: FILT_DECL owns identifiers a0..a3,b0..b3,c0..c3,d0..d3.

#define FILT_DECL(h)                                          \
  const float a0 = h[6], a1 = h[4], a2 = h[2], a3 = h[0];     \
  const float b0 = h[7], b1 = h[5], b2 = h[3], b3 = h[1];     \
  const float c0 = h[1], c1 = h[3], c2 = h[5], c3 = h[7];     \
  const float d0 = -h[0], d1 = -h[2], d2 = -h[4], d3 = -h[6];

#define Y0(s0,s1,s2,s3,w0,w1,w2,w3)                                        \
  fmaf(w3, c3, fmaf(w2, c2, fmaf(w1, c1, fmaf(w0, c0,                      \
  fmaf(s3, a3, fmaf(s2, a2, fmaf(s1, a1, s0 * a0)))))))
#define Y1(s0,s1,s2,s3,w0,w1,w2,w3)                                        \
  fmaf(w3, d3, fmaf(w2, d2, fmaf(w1, d1, fmaf(w0, d0,                      \
  fmaf(s3, b3, fmaf(s2, b2, fmaf(s1, b1, s0 * b0)))))))

// ---------------- pass 1: axis 1 (row stride 65536), scalar, in -> tmp ----
// Dense-row-coverage grid (256,2,4): each (y,z) covers a full 256 KB row
// densely (256 blocks x 1 KB); only 32 live row-streams. NT loads keep the
// read-once x out of L3 so tmp stays L3-resident for pass 2.
__global__ __launch_bounds__(256) void wav_axis1_s(const float* __restrict__ in,
                                                   float* __restrict__ tmp,
                                                   const float* __restrict__ h) {
  const int inner = blockIdx.x * 256 + threadIdx.x;
  const int m0 = blockIdx.y * 64;
  const size_t base = (size_t)blockIdx.z * (256u * 65536u) + (unsigned)inner;
  const float* __restrict__ ps = in + base;
  const float* __restrict__ pw = in + base + (size_t)128 * 65536;
  float* __restrict__ po = tmp + base;
  FILT_DECL(h)
  float s0 = __builtin_nontemporal_load(&ps[(size_t)((m0 - 3) & 127) * 65536]);
  float s1 = __builtin_nontemporal_load(&ps[(size_t)((m0 - 2) & 127) * 65536]);
  float s2 = __builtin_nontemporal_load(&ps[(size_t)((m0 - 1) & 127) * 65536]);
  float w0 = __builtin_nontemporal_load(&pw[(size_t)((m0 - 3) & 127) * 65536]);
  float w1 = __builtin_nontemporal_load(&pw[(size_t)((m0 - 2) & 127) * 65536]);
  float w2 = __builtin_nontemporal_load(&pw[(size_t)((m0 - 1) & 127) * 65536]);
  for (int m = m0; m < m0 + 64; ++m) {
    const float s3 = __builtin_nontemporal_load(&ps[(size_t)m * 65536]);
    const float w3 = __builtin_nontemporal_load(&pw[(size_t)m * 65536]);
    po[(size_t)(2 * m) * 65536] = Y0(s0, s1, s2, s3, w0, w1, w2, w3);
    po[(size_t)(2 * m + 1) * 65536] = Y1(s0, s1, s2, s3, w0, w1, w2, w3);
    s0 = s1; s1 = s2; s2 = s3;
    w0 = w1; w1 = w2; w2 = w3;
  }
}

// ---------------- pass 2: fused axes 2+3 per (b,d1) slice, tmp -> out -----
// Output tile 32 (d2) x 128 (d3); staged footprint 38 x 134 wrapped, 20.8 KB.
// axis-2: one thread per column (dead-slot in-place, thread-exclusive).
// axis-3: 32 rows x 8 pair-chunks = 256 threads, plain float4 stores.
__global__ __launch_bounds__(256, 4) void wav_t23(const float* __restrict__ tmp,
                                                  float* __restrict__ out,
                                                  const float* __restrict__ hg) {
  __shared__ float lb[38 * 137];                 // stride 137 (odd) vs banks
  const int t = threadIdx.x;
  const int d2t = blockIdx.x & 7;                // 8 tiles of 32 rows
  const int d3t = blockIdx.x >> 3;               // 2 tiles of 128 cols
  const size_t slice = blockIdx.y;               // b*256 + d1
  const float* __restrict__ src = tmp + slice * 65536;
  FILT_DECL(hg)
  const int mb2 = 16 * d2t - 3;
  const int mb3 = 64 * d3t - 3;

  // stage (38 i2) x (134 i3): s|w halves wrapped per axis
  for (int e = t; e < 38 * 134; e += 256) {
    const int i2 = e / 134, i3 = e - i2 * 134;
    const int g2 = (i2 < 19) ? ((mb2 + i2) & 127) : (128 + ((mb2 + i2 - 19) & 127));
    const int g3 = (i3 < 67) ? ((mb3 + i3) & 127) : (128 + ((mb3 + i3 - 67) & 127));
    lb[i2 * 137 + i3] = src[g2 * 256 + g3];
  }
  __syncthreads();

  // axis-2 down columns (rows 0..18 = s, 19..37 = w); dead-slot in place:
  // pair p: y[2p] -> row p, y[2p+1] -> row 19+p (row p dead after pair p).
  if (t < 134) {
    float S[19], W[19];
#pragma unroll
    for (int i = 0; i < 19; ++i) S[i] = lb[i * 137 + t];
#pragma unroll
    for (int i = 0; i < 19; ++i) W[i] = lb[(19 + i) * 137 + t];
#pragma unroll
    for (int p = 0; p < 16; ++p) {
      lb[p * 137 + t]        = Y0(S[p], S[p+1], S[p+2], S[p+3], W[p], W[p+1], W[p+2], W[p+3]);
      lb[(19 + p) * 137 + t] = Y1(S[p], S[p+1], S[p+2], S[p+3], W[p], W[p+1], W[p+2], W[p+3]);
    }
  }
  __syncthreads();

  // axis-3 along rows; local out row r -> phys row (r&1 ? 19+(r>>1) : r>>1)
  const int r = t >> 3, pc = t & 7;
  const int prow = ((r & 1) ? (19 + (r >> 1)) : (r >> 1)) * 137;
  const int cc0 = 8 * pc;                        // pairs 8*pc .. 8*pc+7
  float S[11], W[11];
#pragma unroll
  for (int i = 0; i < 11; ++i) S[i] = lb[prow + cc0 + i];
#pragma unroll
  for (int i = 0; i < 11; ++i) W[i] = lb[prow + 67 + cc0 + i];
  float y[16];
#pragma unroll
  for (int q = 0; q < 8; ++q) {
    y[2*q]   = Y0(S[q], S[q+1], S[q+2], S[q+3], W[q], W[q+1], W[q+2], W[q+3]);
    y[2*q+1] = Y1(S[q], S[q+1], S[q+2], S[q+3], W[q], W[q+1], W[q+2], W[q+3]);
  }
  float* __restrict__ dst = out + slice * 65536
      + (size_t)(32 * d2t + r) * 256 + 128 * d3t + 16 * pc;
#pragma unroll
  for (int v = 0; v < 4; ++v)
    *reinterpret_cast<float4*>(dst + 4 * v) =
        make_float4(y[4*v], y[4*v+1], y[4*v+2], y[4*v+3]);
}

// ================= fallback 3-pass (verified round 2) =================
__global__ __launch_bounds__(256) void wav_axis1(const float* __restrict__ in,
                                                 float* __restrict__ out,
                                                 const float* __restrict__ h) {
  const int inner = blockIdx.x * 256 + threadIdx.x;
  const int m0 = blockIdx.y * 64;
  const size_t base = (size_t)blockIdx.z * (256u * 65536u) + (unsigned)inner;
  const float* __restrict__ ps = in + base;
  const float* __restrict__ pw = in + base + (size_t)128 * 65536;
  float* __restrict__ po = out + base;
  FILT_DECL(h)
  float s0 = ps[(size_t)((m0 - 3) & 127) * 65536];
  float s1 = ps[(size_t)((m0 - 2) & 127) * 65536];
  float s2 = ps[(size_t)((m0 - 1) & 127) * 65536];
  float w0 = pw[(size_t)((m0 - 3) & 127) * 65536];
  float w1 = pw[(size_t)((m0 - 2) & 127) * 65536];
  float w2 = pw[(size_t)((m0 - 1) & 127) * 65536];
  for (int m = m0; m < m0 + 64; ++m) {
    const float s3 = ps[(size_t)m * 65536];
    const float w3 = pw[(size_t)m * 65536];
    po[(size_t)(2 * m) * 65536] = Y0(s0, s1, s2, s3, w0, w1, w2, w3);
    po[(size_t)(2 * m + 1) * 65536] = Y1(s0, s1, s2, s3, w0, w1, w2, w3);
    s0 = s1; s1 = s2; s2 = s3;
    w0 = w1; w1 = w2; w2 = w3;
  }
}

__global__ __launch_bounds__(256) void wav_axis2(float* __restrict__ buf,
                                                 const float* __restrict__ h) {
  __shared__ float tile[256][32];
  const int t = threadIdx.x;
  const int c = t & 31;
  const int g = t >> 5;
  const size_t slice = (size_t)(blockIdx.x >> 3);
  const int col0 = (blockIdx.x & 7) * 32;
  float* __restrict__ p = buf + slice * 65536 + col0;
#pragma unroll
  for (int i = 0; i < 32; ++i) {
    const int rr = i * 8 + g;
    tile[rr][c] = p[rr * 256 + c];
  }
  __syncthreads();
  FILT_DECL(h)
  const int m0 = g * 16;
  float s0 = tile[(m0 - 3) & 127][c];
  float s1 = tile[(m0 - 2) & 127][c];
  float s2 = tile[(m0 - 1) & 127][c];
  float w0 = tile[128 + ((m0 - 3) & 127)][c];
  float w1 = tile[128 + ((m0 - 2) & 127)][c];
  float w2 = tile[128 + ((m0 - 1) & 127)][c];
#pragma unroll
  for (int m = m0; m < m0 + 16; ++m) {
    const float s3 = tile[m][c];
    const float w3 = tile[128 + m][c];
    p[(2 * m) * 256 + c] = Y0(s0, s1, s2, s3, w0, w1, w2, w3);
    p[(2 * m + 1) * 256 + c] = Y1(s0, s1, s2, s3, w0, w1, w2, w3);
    s0 = s1; s1 = s2; s2 = s3;
    w0 = w1; w1 = w2; w2 = w3;
  }
}

__global__ __launch_bounds__(256) void wav_axis3(float* __restrict__ buf,
                                                 const float* __restrict__ h) {
  __shared__ float tile[512];
  const int t = threadIdx.x;
  float* __restrict__ p = buf + (size_t)blockIdx.x * 512;
  tile[t] = p[t];
  tile[256 + t] = p[256 + t];
  __syncthreads();
  FILT_DECL(h)
  const int rr = t >> 7;
  const int m = t & 127;
  const float* __restrict__ line = tile + rr * 256;
  const float s0 = line[(m - 3) & 127];
  const float s1 = line[(m - 2) & 127];
  const float s2 = line[(m - 1) & 127];
  const float s3 = line[m];
  const float w0 = line[128 + ((m - 3) & 127)];
  const float w1 = line[128 + ((m - 2) & 127)];
  const float w2 = line[128 + ((m - 1) & 127)];
  const float w3 = line[128 + m];
  float2 y;
  y.x = Y0(s0, s1, s2, s3, w0, w1, w2, w3);
  y.y = Y1(s0, s1, s2, s3, w0, w1, w2, w3);
  *reinterpret_cast<float2*>(p + rr * 256 + 2 * m) = y;
}

extern "C" void kernel_launch(void* const* d_in, const int* in_sizes, int n_in,
                              void* d_out, int out_size, void* d_ws, size_t ws_size,
                              hipStream_t stream) {
  const float* x = (const float*)d_in[0];
  const float* h = (const float*)d_in[1];
  float* out = (float*)d_out;
  const size_t need = (size_t)4 * 256 * 256 * 256 * 4;   // 268 MB intermediate

  if (ws_size >= need) {
    float* tmp = (float*)d_ws;
    wav_axis1_s<<<dim3(256, 2, 4), 256, 0, stream>>>(x, tmp, h);
    wav_t23<<<dim3(16, 1024), 256, 0, stream>>>(tmp, out, h);
  } else {
    wav_axis1<<<dim3(256, 2, 4), 256, 0, stream>>>(x, out, h);
    wav_axis2<<<dim3(8192), 256, 0, stream>>>(out, h);
    wav_axis3<<<dim3(131072), 256, 0, stream>>>(out, h);
  }
}

// Round 9
// 223.464 us; speedup vs baseline: 2.1798x; 1.0950x over previous
//
#include <hip/hip_runtime.h>

// Inverse 3D DWT (DB4, periodization), (4,256,256,256) fp32.
// pass 1: axis-1 streaming transform, x -> ws (scalar, dense-row-coverage grid,
//         NT loads of x; measured ~6.1 TB/s, at roofline)
// pass 2: fused axis-2 + axis-3 per (b,d1) slice, ws -> out.
//         Tile = 32 (d2) x 256 (full d3): d3 wrap internal -> no d3 halo,
//         staging index math is shifts/masks, axis-2 uses ALL 512 threads
//         (2 threads per column; same-wave lockstep + program order make the
//         dead-slot in-place update race-free).
// Polyphase: y[2m]   = sum_j s[(m+j-3)&127]*a[j] + w[..]*c[j]
//            y[2m+1] = sum_j s[(m+j-3)&127]*b[j] + w[..]*d[j]
// a[j]=h[6-2j], b[j]=h[7-2j], c[j]=h[2j+1], d[j]=-h[2j].
// NOTE: FILT_DECL owns identifiers a0..a3,b0..b3,c0..c3,d0..d3.

#define FILT_DECL(h)                                          \
  const float a0 = h[6], a1 = h[4], a2 = h[2], a3 = h[0];     \
  const float b0 = h[7], b1 = h[5], b2 = h[3], b3 = h[1];     \
  const float c0 = h[1], c1 = h[3], c2 = h[5], c3 = h[7];     \
  const float d0 = -h[0], d1 = -h[2], d2 = -h[4], d3 = -h[6];

#define Y0(s0,s1,s2,s3,w0,w1,w2,w3)                                        \
  fmaf(w3, c3, fmaf(w2, c2, fmaf(w1, c1, fmaf(w0, c0,                      \
  fmaf(s3, a3, fmaf(s2, a2, fmaf(s1, a1, s0 * a0)))))))
#define Y1(s0,s1,s2,s3,w0,w1,w2,w3)                                        \
  fmaf(w3, d3, fmaf(w2, d2, fmaf(w1, d1, fmaf(w0, d0,                      \
  fmaf(s3, b3, fmaf(s2, b2, fmaf(s1, b1, s0 * b0)))))))

// ---------------- pass 1: axis 1 (row stride 65536), scalar, in -> tmp ----
__global__ __launch_bounds__(256) void wav_axis1_s(const float* __restrict__ in,
                                                   float* __restrict__ tmp,
                                                   const float* __restrict__ h) {
  const int inner = blockIdx.x * 256 + threadIdx.x;
  const int m0 = blockIdx.y * 64;
  const size_t base = (size_t)blockIdx.z * (256u * 65536u) + (unsigned)inner;
  const float* __restrict__ ps = in + base;
  const float* __restrict__ pw = in + base + (size_t)128 * 65536;
  float* __restrict__ po = tmp + base;
  FILT_DECL(h)
  float s0 = __builtin_nontemporal_load(&ps[(size_t)((m0 - 3) & 127) * 65536]);
  float s1 = __builtin_nontemporal_load(&ps[(size_t)((m0 - 2) & 127) * 65536]);
  float s2 = __builtin_nontemporal_load(&ps[(size_t)((m0 - 1) & 127) * 65536]);
  float w0 = __builtin_nontemporal_load(&pw[(size_t)((m0 - 3) & 127) * 65536]);
  float w1 = __builtin_nontemporal_load(&pw[(size_t)((m0 - 2) & 127) * 65536]);
  float w2 = __builtin_nontemporal_load(&pw[(size_t)((m0 - 1) & 127) * 65536]);
  for (int m = m0; m < m0 + 64; ++m) {
    const float s3 = __builtin_nontemporal_load(&ps[(size_t)m * 65536]);
    const float w3 = __builtin_nontemporal_load(&pw[(size_t)m * 65536]);
    po[(size_t)(2 * m) * 65536] = Y0(s0, s1, s2, s3, w0, w1, w2, w3);
    po[(size_t)(2 * m + 1) * 65536] = Y1(s0, s1, s2, s3, w0, w1, w2, w3);
    s0 = s1; s1 = s2; s2 = s3;
    w0 = w1; w1 = w2; w2 = w3;
  }
}

// ---------------- pass 2: fused axes 2+3, full-width tile, tmp -> out -----
// Tile 32 (d2) x 256 (d3); staged 38 rows x 256 cols, LDS stride 257.
__global__ __launch_bounds__(512, 8) void wav_t23w(const float* __restrict__ tmp,
                                                   float* __restrict__ out,
                                                   const float* __restrict__ hg) {
  __shared__ float lb[38 * 257];                 // 39.1 KB
  __shared__ int gg2[38];
  const int t = threadIdx.x;
  const int d2t = blockIdx.x;                    // 0..7 (32 d2-rows each)
  const size_t slice = blockIdx.y;               // b*256 + d1
  const float* __restrict__ src = tmp + slice * 65536;
  FILT_DECL(hg)
  const int mb2 = 16 * d2t - 3;

  if (t < 38) {
    const int g2 = (t < 19) ? ((mb2 + t) & 127) : (128 + ((mb2 + t - 19) & 127));
    gg2[t] = g2 << 8;
  }
  __syncthreads();

  // stage: 38*256 = 9728 = 19 * 512 elements, coalesced rows
  for (int k = 0; k < 19; ++k) {
    const int e = t + 512 * k;
    const int i2 = e >> 8, i3 = e & 255;
    lb[i2 * 257 + i3] = src[gg2[i2] + i3];
  }
  __syncthreads();

  // axis-2: 256 columns x 2 half-threads; col j = t>>1, pairs p0..p0+7.
  // Dead-slot in-place: pair p writes y0->row p, y1->row 19+p.
  // Race-free: both halves of a column are in the same wave; all LDS reads
  // precede all LDS writes in program order.
  {
    const int j = t >> 1, p0 = (t & 1) * 8;
    float S[11], W[11];
#pragma unroll
    for (int i = 0; i < 11; ++i) S[i] = lb[(p0 + i) * 257 + j];
#pragma unroll
    for (int i = 0; i < 11; ++i) W[i] = lb[(19 + p0 + i) * 257 + j];
#pragma unroll
    for (int q = 0; q < 8; ++q) {
      const int p = p0 + q;
      lb[p * 257 + j]        = Y0(S[q], S[q+1], S[q+2], S[q+3], W[q], W[q+1], W[q+2], W[q+3]);
      lb[(19 + p) * 257 + j] = Y1(S[q], S[q+1], S[q+2], S[q+3], W[q], W[q+1], W[q+2], W[q+3]);
    }
  }
  __syncthreads();

  // axis-3: r = t>>4 (0..31 local d2 row), 8 pairs starting at m0 = 8*(t&15).
  // Local out row r lives at phys row (r&1 ? 19+(r>>1) : r>>1).
  const int r = t >> 4, m0 = (t & 15) * 8;
  const int prow = ((r & 1) ? (19 + (r >> 1)) : (r >> 1)) * 257;
  float S[11], W[11];
#pragma unroll
  for (int i = 0; i < 11; ++i) {
    const int cs = (m0 + i - 3) & 127;
    S[i] = lb[prow + cs];
    W[i] = lb[prow + 128 + cs];
  }
  float* __restrict__ dst = out + slice * 65536
      + (size_t)(32 * d2t + r) * 256 + 16 * (t & 15);
#pragma unroll
  for (int g = 0; g < 4; ++g) {
    float4 y;
    y.x = Y0(S[2*g],   S[2*g+1], S[2*g+2], S[2*g+3], W[2*g],   W[2*g+1], W[2*g+2], W[2*g+3]);
    y.y = Y1(S[2*g],   S[2*g+1], S[2*g+2], S[2*g+3], W[2*g],   W[2*g+1], W[2*g+2], W[2*g+3]);
    y.z = Y0(S[2*g+1], S[2*g+2], S[2*g+3], S[2*g+4], W[2*g+1], W[2*g+2], W[2*g+3], W[2*g+4]);
    y.w = Y1(S[2*g+1], S[2*g+2], S[2*g+3], S[2*g+4], W[2*g+1], W[2*g+2], W[2*g+3], W[2*g+4]);
    *reinterpret_cast<float4*>(dst + 4 * g) = y;
  }
}

// ================= fallback 3-pass (verified round 2) =================
__global__ __launch_bounds__(256) void wav_axis1(const float* __restrict__ in,
                                                 float* __restrict__ out,
                                                 const float* __restrict__ h) {
  const int inner = blockIdx.x * 256 + threadIdx.x;
  const int m0 = blockIdx.y * 64;
  const size_t base = (size_t)blockIdx.z * (256u * 65536u) + (unsigned)inner;
  const float* __restrict__ ps = in + base;
  const float* __restrict__ pw = in + base + (size_t)128 * 65536;
  float* __restrict__ po = out + base;
  FILT_DECL(h)
  float s0 = ps[(size_t)((m0 - 3) & 127) * 65536];
  float s1 = ps[(size_t)((m0 - 2) & 127) * 65536];
  float s2 = ps[(size_t)((m0 - 1) & 127) * 65536];
  float w0 = pw[(size_t)((m0 - 3) & 127) * 65536];
  float w1 = pw[(size_t)((m0 - 2) & 127) * 65536];
  float w2 = pw[(size_t)((m0 - 1) & 127) * 65536];
  for (int m = m0; m < m0 + 64; ++m) {
    const float s3 = ps[(size_t)m * 65536];
    const float w3 = pw[(size_t)m * 65536];
    po[(size_t)(2 * m) * 65536] = Y0(s0, s1, s2, s3, w0, w1, w2, w3);
    po[(size_t)(2 * m + 1) * 65536] = Y1(s0, s1, s2, s3, w0, w1, w2, w3);
    s0 = s1; s1 = s2; s2 = s3;
    w0 = w1; w1 = w2; w2 = w3;
  }
}

__global__ __launch_bounds__(256) void wav_axis2(float* __restrict__ buf,
                                                 const float* __restrict__ h) {
  __shared__ float tile[256][32];
  const int t = threadIdx.x;
  const int c = t & 31;
  const int g = t >> 5;
  const size_t slice = (size_t)(blockIdx.x >> 3);
  const int col0 = (blockIdx.x & 7) * 32;
  float* __restrict__ p = buf + slice * 65536 + col0;
#pragma unroll
  for (int i = 0; i < 32; ++i) {
    const int rr = i * 8 + g;
    tile[rr][c] = p[rr * 256 + c];
  }
  __syncthreads();
  FILT_DECL(h)
  const int m0 = g * 16;
  float s0 = tile[(m0 - 3) & 127][c];
  float s1 = tile[(m0 - 2) & 127][c];
  float s2 = tile[(m0 - 1) & 127][c];
  float w0 = tile[128 + ((m0 - 3) & 127)][c];
  float w1 = tile[128 + ((m0 - 2) & 127)][c];
  float w2 = tile[128 + ((m0 - 1) & 127)][c];
#pragma unroll
  for (int m = m0; m < m0 + 16; ++m) {
    const float s3 = tile[m][c];
    const float w3 = tile[128 + m][c];
    p[(2 * m) * 256 + c] = Y0(s0, s1, s2, s3, w0, w1, w2, w3);
    p[(2 * m + 1) * 256 + c] = Y1(s0, s1, s2, s3, w0, w1, w2, w3);
    s0 = s1; s1 = s2; s2 = s3;
    w0 = w1; w1 = w2; w2 = w3;
  }
}

__global__ __launch_bounds__(256) void wav_axis3(float* __restrict__ buf,
                                                 const float* __restrict__ h) {
  __shared__ float tile[512];
  const int t = threadIdx.x;
  float* __restrict__ p = buf + (size_t)blockIdx.x * 512;
  tile[t] = p[t];
  tile[256 + t] = p[256 + t];
  __syncthreads();
  FILT_DECL(h)
  const int rr = t >> 7;
  const int m = t & 127;
  const float* __restrict__ line = tile + rr * 256;
  const float s0 = line[(m - 3) & 127];
  const float s1 = line[(m - 2) & 127];
  const float s2 = line[(m - 1) & 127];
  const float s3 = line[m];
  const float w0 = line[128 + ((m - 3) & 127)];
  const float w1 = line[128 + ((m - 2) & 127)];
  const float w2 = line[128 + ((m - 1) & 127)];
  const float w3 = line[128 + m];
  float2 y;
  y.x = Y0(s0, s1, s2, s3, w0, w1, w2, w3);
  y.y = Y1(s0, s1, s2, s3, w0, w1, w2, w3);
  *reinterpret_cast<float2*>(p + rr * 256 + 2 * m) = y;
}

extern "C" void kernel_launch(void* const* d_in, const int* in_sizes, int n_in,
                              void* d_out, int out_size, void* d_ws, size_t ws_size,
                              hipStream_t stream) {
  const float* x = (const float*)d_in[0];
  const float* h = (const float*)d_in[1];
  float* out = (float*)d_out;
  const size_t need = (size_t)4 * 256 * 256 * 256 * 4;   // 268 MB intermediate

  if (ws_size >= need) {
    float* tmp = (float*)d_ws;
    wav_axis1_s<<<dim3(256, 2, 4), 256, 0, stream>>>(x, tmp, h);
    wav_t23w<<<dim3(8, 1024), 512, 0, stream>>>(tmp, out, h);
  } else {
    wav_axis1<<<dim3(256, 2, 4), 256, 0, stream>>>(x, out, h);
    wav_axis2<<<dim3(8192), 256, 0, stream>>>(out, h);
    wav_axis3<<<dim3(131072), 256, 0, stream>>>(out, h);
  }
}